// Round 2
// baseline (158.994 us; speedup 1.0000x reference)
//
#include <hip/hip_runtime.h>
#include <math.h>

// Problem constants
#define BATCH 1024
#define FEAT  512
#define NT    64
#define DDIM  1024          // CSETSIZE(64) * Nrf(4) * Nrf(4)
#define NCOLS 2112          // 64 (theta) + 1024 (D_r) + 1024 (D_i)
#define BK    16
#define LDSS  68            // 64 + 4 pad (keeps float4 alignment: 68*4 = 272 = 17*16)

// ---------------------------------------------------------------------------
// GEMM: C[b, n] = x[b,:] . W[n,:] + bias[n], where W/bias are the concatenation
// of (W_A,b_A | W_Dr,b_Dr | W_Di,b_Di). Column tiles of 64 fall entirely inside
// one segment (64 = 1 tile, 1024 = 16 tiles each), so each block uses one W ptr.
// 64x64 tile / block, 256 threads, 4x4 accumulators per thread, K staged in LDS
// k-major so fragment reads are ds_read_b128.
// ---------------------------------------------------------------------------
__global__ __launch_bounds__(256) void gemm_kernel(
    const float* __restrict__ x,
    const float* __restrict__ W_A,  const float* __restrict__ b_A,
    const float* __restrict__ W_Dr, const float* __restrict__ b_Dr,
    const float* __restrict__ W_Di, const float* __restrict__ b_Di,
    float* __restrict__ C)
{
    __shared__ __align__(16) float As[BK][LDSS];
    __shared__ __align__(16) float Bs[BK][LDSS];

    const int bx  = blockIdx.x;   // col tile 0..32
    const int by  = blockIdx.y;   // row tile 0..15
    const int tid = threadIdx.x;

    const float* W;
    const float* bias;
    int woff;
    if (bx == 0)        { W = W_A;  bias = b_A;  woff = 0; }
    else if (bx <= 16)  { W = W_Dr; bias = b_Dr; woff = (bx - 1) * 64; }
    else                { W = W_Di; bias = b_Di; woff = (bx - 17) * 64; }

    const int row0 = by * 64;
    const int col0 = bx * 64;

    // staging load assignment: 64 rows x 16 k, float4 per thread
    const int lrow = tid >> 2;        // 0..63
    const int lk   = (tid & 3) * 4;   // 0,4,8,12
    const float* xg = x + (size_t)(row0 + lrow) * FEAT + lk;
    const float* wg = W + (size_t)(woff + lrow) * FEAT + lk;

    // compute assignment: 4 consecutive rows, 4 consecutive cols
    const int r0 = (tid & 15) * 4;
    const int c0 = (tid >> 4) * 4;

    float acc[4][4] = {};

    for (int k0 = 0; k0 < FEAT; k0 += BK) {
        const float4 av = *(const float4*)(xg + k0);
        const float4 bv = *(const float4*)(wg + k0);
        __syncthreads();               // previous iter's reads done
        As[lk + 0][lrow] = av.x; As[lk + 1][lrow] = av.y;
        As[lk + 2][lrow] = av.z; As[lk + 3][lrow] = av.w;
        Bs[lk + 0][lrow] = bv.x; Bs[lk + 1][lrow] = bv.y;
        Bs[lk + 2][lrow] = bv.z; Bs[lk + 3][lrow] = bv.w;
        __syncthreads();

        #pragma unroll
        for (int k = 0; k < BK; ++k) {
            const float4 a4 = *(const float4*)&As[k][r0];
            const float4 b4 = *(const float4*)&Bs[k][c0];
            const float a[4] = {a4.x, a4.y, a4.z, a4.w};
            const float b[4] = {b4.x, b4.y, b4.z, b4.w};
            #pragma unroll
            for (int i = 0; i < 4; ++i)
                #pragma unroll
                for (int j = 0; j < 4; ++j)
                    acc[i][j] += a[i] * b[j];
        }
    }

    const float4 bs = *(const float4*)(bias + woff + c0);   // FIXED: was bias + c0
    #pragma unroll
    for (int i = 0; i < 4; ++i) {
        float4 o;
        o.x = acc[i][0] + bs.x;
        o.y = acc[i][1] + bs.y;
        o.z = acc[i][2] + bs.z;
        o.w = acc[i][3] + bs.w;
        *(float4*)(C + (size_t)(row0 + r0 + i) * NCOLS + col0 + c0) = o;
    }
}

// ---------------------------------------------------------------------------
// A_real/A_imag fill: per batch row, 64x64 diagonal matrices of cos/sin(theta).
// One block per b; float4 stores, diag element patched when inside the chunk.
// ---------------------------------------------------------------------------
__global__ __launch_bounds__(256) void afill_kernel(
    const float* __restrict__ C, float* __restrict__ out)
{
    const int b   = blockIdx.x;
    const int tid = threadIdx.x;
    const float* theta = C + (size_t)b * NCOLS;   // cols 0..63, bias included
    float* ar = out + (size_t)b * 4096;
    float* ai = out + (size_t)BATCH * 4096 + (size_t)b * 4096;

    #pragma unroll
    for (int it = 0; it < 4; ++it) {
        const int idx = tid + it * 256;           // float4 chunk id, 0..1023
        const int t  = idx >> 4;                  // row within 64x64
        const int j0 = (idx & 15) * 4;            // first col of chunk
        float4 vr = {0.f, 0.f, 0.f, 0.f};
        float4 vi = {0.f, 0.f, 0.f, 0.f};
        if (t >= j0 && t < j0 + 4) {
            float s, c;
            sincosf(theta[t], &s, &c);
            ((float*)&vr)[t - j0] = c;
            ((float*)&vi)[t - j0] = s;
        }
        ((float4*)ar)[idx] = vr;
        ((float4*)ai)[idx] = vi;
    }
}

// ---------------------------------------------------------------------------
// D normalize: per (b,c), V_F = sqrt(8 * sum_{16}(Dr^2 + Di^2)); out = 2*D/V_F.
// One block per b, 256 threads = 64 c's x 4 threads, float4 per thread.
// ---------------------------------------------------------------------------
__global__ __launch_bounds__(256) void dnorm_kernel(
    const float* __restrict__ C, float* __restrict__ out)
{
    const int b   = blockIdx.x;
    const int tid = threadIdx.x;
    const float* dr = C + (size_t)b * NCOLS + 64;
    const float* di = C + (size_t)b * NCOLS + 64 + DDIM;

    const int c  = tid >> 2;            // 0..63
    const int e0 = (tid & 3) * 4;       // 0,4,8,12 within the 16-elem block

    const float4 r  = *(const float4*)(dr + c * 16 + e0);
    const float4 im = *(const float4*)(di + c * 16 + e0);

    float p = r.x * r.x + r.y * r.y + r.z * r.z + r.w * r.w
            + im.x * im.x + im.y * im.y + im.z * im.z + im.w * im.w;
    p += __shfl_xor(p, 1);
    p += __shfl_xor(p, 2);              // lanes 4c..4c+3 now hold full sum

    const float scale = 2.0f / sqrtf(8.0f * p);

    const size_t drn = (size_t)2 * BATCH * 4096;
    const size_t din = drn + (size_t)BATCH * DDIM;
    float4 orr = {r.x * scale, r.y * scale, r.z * scale, r.w * scale};
    float4 oii = {im.x * scale, im.y * scale, im.z * scale, im.w * scale};
    *(float4*)(out + drn + (size_t)b * DDIM + c * 16 + e0) = orr;
    *(float4*)(out + din + (size_t)b * DDIM + c * 16 + e0) = oii;
}

// ---------------------------------------------------------------------------
// CSet pass-through: 16384 floats.
// ---------------------------------------------------------------------------
__global__ __launch_bounds__(256) void cset_copy_kernel(
    const float* __restrict__ cset, float* __restrict__ out)
{
    const int idx = blockIdx.x * 256 + threadIdx.x;   // 0..4095 float4 chunks
    const size_t base = (size_t)2 * BATCH * 4096 + (size_t)2 * BATCH * DDIM;
    ((float4*)(out + base))[idx] = ((const float4*)cset)[idx];
}

extern "C" void kernel_launch(void* const* d_in, const int* in_sizes, int n_in,
                              void* d_out, int out_size, void* d_ws, size_t ws_size,
                              hipStream_t stream) {
    const float* x    = (const float*)d_in[0];
    const float* W_A  = (const float*)d_in[1];
    const float* b_A  = (const float*)d_in[2];
    const float* W_Dr = (const float*)d_in[3];
    const float* b_Dr = (const float*)d_in[4];
    const float* W_Di = (const float*)d_in[5];
    const float* b_Di = (const float*)d_in[6];
    const float* CSet = (const float*)d_in[7];
    float* out = (float*)d_out;
    float* C   = (float*)d_ws;   // BATCH x NCOLS fp32 = 8.65 MB scratch

    dim3 ggrid(33, 16);
    gemm_kernel<<<ggrid, 256, 0, stream>>>(x, W_A, b_A, W_Dr, b_Dr, W_Di, b_Di, C);
    afill_kernel<<<BATCH, 256, 0, stream>>>(C, out);
    dnorm_kernel<<<BATCH, 256, 0, stream>>>(C, out);
    cset_copy_kernel<<<16, 256, 0, stream>>>(CSet, out);
}

// Round 3
// 127.429 us; speedup vs baseline: 1.2477x; 1.2477x over previous
//
#include <hip/hip_runtime.h>
#include <math.h>

// Problem constants
#define BATCH 1024
#define FEAT  512
#define NT    64
#define DDIM  1024          // CSETSIZE(64) * Nrf(4) * Nrf(4)
#define BKA   32
#define LDSS  68            // 64 + 4 pad, keeps 16B row alignment (68*4=272)

// Output layout (flat):
//   A_real : [0,                    BATCH*4096)
//   A_imag : [BATCH*4096,           2*BATCH*4096)
//   D_r_n  : [2*BATCH*4096,         2*BATCH*4096 +   BATCH*1024)
//   D_i_n  : [... + BATCH*1024,     ... + 2*BATCH*1024)
//   CSet   : last 16384 floats

// ---------------------------------------------------------------------------
// ONE fused kernel, heterogeneous blocks:
//   blocks [0,256):    D-GEMM + Frobenius-norm epilogue.
//                      Block (bx=bid&15, by=bid>>4) computes rows by*64..+63 of
//                      Dr cols bx*64..+63 AND Di cols bx*64..+63 (shared x tile),
//                      then V_F = sqrt(8*sum_16(Dr^2+Di^2)) per (row,c) via
//                      in-wave shuffles, writes 2*D/V_F directly to out.
//   blocks [256,1280): per-batch-row A_real/A_imag diagonal fill; theta is
//                      recomputed from x[b]·W_A (W_A is L2-resident, 65K FLOP).
//                      Blocks 256..271 also copy CSet.
// ---------------------------------------------------------------------------
__global__ __launch_bounds__(256) void fused_kernel(
    const float* __restrict__ x,
    const float* __restrict__ W_A,  const float* __restrict__ b_A,
    const float* __restrict__ W_Dr, const float* __restrict__ b_Dr,
    const float* __restrict__ W_Di, const float* __restrict__ b_Di,
    const float* __restrict__ cset,
    float* __restrict__ out)
{
    const int bid = blockIdx.x;
    const int tid = threadIdx.x;

    if (bid < 256) {
        // ------------------------- D-GEMM + norm path -------------------------
        __shared__ __align__(16) float As [BKA][LDSS];
        __shared__ __align__(16) float Brs[BKA][LDSS];
        __shared__ __align__(16) float Bis[BKA][LDSS];

        const int bx = bid & 15;         // col tile (64 cols of Dr and of Di)
        const int by = bid >> 4;         // row tile
        const int row0 = by * 64;
        const int woff = bx * 64;        // row offset into W_Dr/W_Di == D col offset

        // staging: thread loads 2 consecutive float4 per matrix per iter.
        // f0 = tid*2: srow = tid>>2 (0..63), skq = (tid*2)&7 in {0,2,4,6}
        const int srow = tid >> 2;
        const int skq  = (tid * 2) & 7;
        const float* xg  = x    + (size_t)(row0 + srow) * FEAT + skq * 4;
        const float* wrg = W_Dr + (size_t)(woff + srow) * FEAT + skq * 4;
        const float* wig = W_Di + (size_t)(woff + srow) * FEAT + skq * 4;

        // compute map: 4 rows x 4 cols (same local cols for Dr and Di).
        // wave w covers c-groups c0 in {16w,16w+4,16w+8,16w+12} -> one c-block/wave-row
        const int r0 = (tid & 15) * 4;
        const int c0 = (tid >> 4) * 4;

        float accr[4][4] = {};
        float acci[4][4] = {};

        for (int k0 = 0; k0 < FEAT; k0 += BKA) {
            const float4 av0 = *(const float4*)(xg  + k0);
            const float4 av1 = *(const float4*)(xg  + k0 + 4);
            const float4 br0 = *(const float4*)(wrg + k0);
            const float4 br1 = *(const float4*)(wrg + k0 + 4);
            const float4 bi0 = *(const float4*)(wig + k0);
            const float4 bi1 = *(const float4*)(wig + k0 + 4);
            __syncthreads();
            const int kb = skq * 4;
            As [kb+0][srow]=av0.x; As [kb+1][srow]=av0.y; As [kb+2][srow]=av0.z; As [kb+3][srow]=av0.w;
            As [kb+4][srow]=av1.x; As [kb+5][srow]=av1.y; As [kb+6][srow]=av1.z; As [kb+7][srow]=av1.w;
            Brs[kb+0][srow]=br0.x; Brs[kb+1][srow]=br0.y; Brs[kb+2][srow]=br0.z; Brs[kb+3][srow]=br0.w;
            Brs[kb+4][srow]=br1.x; Brs[kb+5][srow]=br1.y; Brs[kb+6][srow]=br1.z; Brs[kb+7][srow]=br1.w;
            Bis[kb+0][srow]=bi0.x; Bis[kb+1][srow]=bi0.y; Bis[kb+2][srow]=bi0.z; Bis[kb+3][srow]=bi0.w;
            Bis[kb+4][srow]=bi1.x; Bis[kb+5][srow]=bi1.y; Bis[kb+6][srow]=bi1.z; Bis[kb+7][srow]=bi1.w;
            __syncthreads();

            #pragma unroll
            for (int k = 0; k < BKA; ++k) {
                const float4 a4  = *(const float4*)&As [k][r0];
                const float4 br4 = *(const float4*)&Brs[k][c0];
                const float4 bi4 = *(const float4*)&Bis[k][c0];
                const float a[4]  = {a4.x, a4.y, a4.z, a4.w};
                const float br[4] = {br4.x, br4.y, br4.z, br4.w};
                const float bi[4] = {bi4.x, bi4.y, bi4.z, bi4.w};
                #pragma unroll
                for (int i = 0; i < 4; ++i) {
                    #pragma unroll
                    for (int j = 0; j < 4; ++j) {
                        accr[i][j] += a[i] * br[j];
                        acci[i][j] += a[i] * bi[j];
                    }
                }
            }
        }

        // bias
        const float4 bsr = *(const float4*)(b_Dr + woff + c0);
        const float4 bsi = *(const float4*)(b_Di + woff + c0);
        const float brv[4] = {bsr.x, bsr.y, bsr.z, bsr.w};
        const float biv[4] = {bsi.x, bsi.y, bsi.z, bsi.w};
        #pragma unroll
        for (int i = 0; i < 4; ++i)
            #pragma unroll
            for (int j = 0; j < 4; ++j) {
                accr[i][j] += brv[j];
                acci[i][j] += biv[j];
            }

        // Frobenius norm per (row, c-block): reduce across the 4 col-groups of
        // this wave (lanes xor 16, 32), then scale = 2/sqrt(8*p).
        const size_t drn = (size_t)2 * BATCH * 4096;
        const size_t din = drn + (size_t)BATCH * DDIM;
        #pragma unroll
        for (int i = 0; i < 4; ++i) {
            float p = 0.f;
            #pragma unroll
            for (int j = 0; j < 4; ++j)
                p += accr[i][j] * accr[i][j] + acci[i][j] * acci[i][j];
            p += __shfl_xor(p, 16);
            p += __shfl_xor(p, 32);
            const float scale = 2.0f / sqrtf(8.0f * p);
            float4 orr, oii;
            orr.x = accr[i][0]*scale; orr.y = accr[i][1]*scale;
            orr.z = accr[i][2]*scale; orr.w = accr[i][3]*scale;
            oii.x = acci[i][0]*scale; oii.y = acci[i][1]*scale;
            oii.z = acci[i][2]*scale; oii.w = acci[i][3]*scale;
            const size_t off = (size_t)(row0 + r0 + i) * DDIM + woff + c0;
            *(float4*)(out + drn + off) = orr;
            *(float4*)(out + din + off) = oii;
        }
    } else {
        // ------------------------- A-fill path -------------------------
        __shared__ float cosT[NT], sinT[NT];
        const int b = bid - 256;
        const int t = tid >> 2;          // antenna 0..63
        const int q = tid & 3;           // quarter of K

        const float* xr = x   + (size_t)b * FEAT + q * 128;
        const float* wr = W_A + (size_t)t * FEAT + q * 128;
        float sum = 0.f;
        #pragma unroll 8
        for (int i = 0; i < 128; i += 4) {
            const float4 xv = *(const float4*)(xr + i);
            const float4 wv = *(const float4*)(wr + i);
            sum += xv.x*wv.x + xv.y*wv.y + xv.z*wv.z + xv.w*wv.w;
        }
        sum += __shfl_xor(sum, 1);
        sum += __shfl_xor(sum, 2);
        if (q == 0) {
            const float theta = sum + b_A[t];
            float s, c;
            sincosf(theta, &s, &c);
            cosT[t] = c; sinT[t] = s;
        }
        __syncthreads();

        float* ar = out + (size_t)b * 4096;
        float* ai = out + (size_t)BATCH * 4096 + (size_t)b * 4096;
        #pragma unroll
        for (int it = 0; it < 4; ++it) {
            const int idx = tid + it * 256;   // float4 chunk 0..1023
            const int tt = idx >> 4;          // row in 64x64
            const int j0 = (idx & 15) * 4;    // first col of chunk
            float4 vr = {0.f, 0.f, 0.f, 0.f};
            float4 vi = {0.f, 0.f, 0.f, 0.f};
            if (tt >= j0 && tt < j0 + 4) {
                ((float*)&vr)[tt - j0] = cosT[tt];
                ((float*)&vi)[tt - j0] = sinT[tt];
            }
            ((float4*)ar)[idx] = vr;
            ((float4*)ai)[idx] = vi;
        }

        // CSet pass-through on the first 16 A-fill blocks
        if (b < 16) {
            const size_t base = (size_t)2 * BATCH * 4096 + (size_t)2 * BATCH * DDIM;
            ((float4*)(out + base))[b * 256 + tid] = ((const float4*)cset)[b * 256 + tid];
        }
    }
}

extern "C" void kernel_launch(void* const* d_in, const int* in_sizes, int n_in,
                              void* d_out, int out_size, void* d_ws, size_t ws_size,
                              hipStream_t stream) {
    const float* x    = (const float*)d_in[0];
    const float* W_A  = (const float*)d_in[1];
    const float* b_A  = (const float*)d_in[2];
    const float* W_Dr = (const float*)d_in[3];
    const float* b_Dr = (const float*)d_in[4];
    const float* W_Di = (const float*)d_in[5];
    const float* b_Di = (const float*)d_in[6];
    const float* CSet = (const float*)d_in[7];
    float* out = (float*)d_out;

    fused_kernel<<<1280, 256, 0, stream>>>(x, W_A, b_A, W_Dr, b_Dr, W_Di, b_Di,
                                           CSet, out);
}